// Round 1
// 735.907 us; speedup vs baseline: 2.2398x; 2.2398x over previous
//
#include <hip/hip_runtime.h>
#include <hip/hip_bf16.h>
#include <cstdint>
#include <cstddef>

#define N_NODES 50000
#define N_EDGES 1600000
#define N_FEAT  512
#define N_HID   256
#define N_CLS   64
#define K_HOPS  10

typedef __attribute__((ext_vector_type(4))) float f32x4;
typedef __attribute__((ext_vector_type(8))) short s16x8;

__device__ __forceinline__ ushort f2bf(float f) {
    uint32_t u = __float_as_uint(f);
    uint32_t r = (u + 0x7FFFu + ((u >> 16) & 1u)) >> 16;
    return (ushort)r;
}

// ---------------- GEMM1: H = relu(X @ W1^T), bf16 MFMA, 128x128 tile, BK=64 ----
__launch_bounds__(256)
__global__ void gemm1_k(const float* __restrict__ X, const float* __restrict__ W1,
                        ushort* __restrict__ H) {
    __shared__ ushort sA[128 * 64];
    __shared__ ushort sB[128 * 64];
    const int m0 = blockIdx.x * 128;
    const int n0 = blockIdx.y * 128;
    const int t = threadIdx.x;
    const int wid = t >> 6, lane = t & 63;
    const int wr = wid >> 1, wc = wid & 1;
    const int lo = lane & 15, hi = lane >> 4;

    f32x4 acc[4][4] = {};

    for (int kt = 0; kt < N_FEAT; kt += 64) {
        // stage A (fp32 -> bf16), 128 rows x 64 k
        #pragma unroll
        for (int p = 0; p < 8; ++p) {
            int idx = p * 256 + t;
            int row = idx >> 4, f4 = idx & 15;
            int grow = m0 + row; if (grow > N_NODES - 1) grow = N_NODES - 1;
            const float4 v = *reinterpret_cast<const float4*>(X + (size_t)grow * N_FEAT + kt + f4 * 4);
            ushort4 h; h.x = f2bf(v.x); h.y = f2bf(v.y); h.z = f2bf(v.z); h.w = f2bf(v.w);
            int g = f4 >> 1;
            int off = row * 64 + (((g ^ (row & 7)) << 3)) + ((f4 & 1) << 2);
            *reinterpret_cast<ushort4*>(&sA[off]) = h;
        }
        // stage B (W1 rows n0..n0+127)
        #pragma unroll
        for (int p = 0; p < 8; ++p) {
            int idx = p * 256 + t;
            int row = idx >> 4, f4 = idx & 15;
            const float4 v = *reinterpret_cast<const float4*>(W1 + (size_t)(n0 + row) * N_FEAT + kt + f4 * 4);
            ushort4 h; h.x = f2bf(v.x); h.y = f2bf(v.y); h.z = f2bf(v.z); h.w = f2bf(v.w);
            int g = f4 >> 1;
            int off = row * 64 + (((g ^ (row & 7)) << 3)) + ((f4 & 1) << 2);
            *reinterpret_cast<ushort4*>(&sB[off]) = h;
        }
        __syncthreads();
        #pragma unroll
        for (int kk = 0; kk < 2; ++kk) {
            const int g = kk * 4 + hi;
            s16x8 a[4], b[4];
            #pragma unroll
            for (int i = 0; i < 4; ++i) {
                int row = wr * 64 + i * 16 + lo;
                a[i] = *reinterpret_cast<const s16x8*>(&sA[row * 64 + ((g ^ (row & 7)) << 3)]);
            }
            #pragma unroll
            for (int j = 0; j < 4; ++j) {
                int row = wc * 64 + j * 16 + lo;
                b[j] = *reinterpret_cast<const s16x8*>(&sB[row * 64 + ((g ^ (row & 7)) << 3)]);
            }
            #pragma unroll
            for (int i = 0; i < 4; ++i)
                #pragma unroll
                for (int j = 0; j < 4; ++j)
                    acc[i][j] = __builtin_amdgcn_mfma_f32_16x16x32_bf16(a[i], b[j], acc[i][j], 0, 0, 0);
        }
        __syncthreads();
    }
    // epilogue: relu + bf16 store
    #pragma unroll
    for (int i = 0; i < 4; ++i) {
        int rbase = m0 + wr * 64 + i * 16 + hi * 4;
        #pragma unroll
        for (int j = 0; j < 4; ++j) {
            int col = n0 + wc * 64 + j * 16 + lo;
            #pragma unroll
            for (int r = 0; r < 4; ++r) {
                int row = rbase + r;
                if (row < N_NODES) {
                    float v = acc[i][j][r];
                    H[(size_t)row * N_HID + col] = f2bf(fmaxf(v, 0.0f));
                }
            }
        }
    }
}

// ---------------- GEMM2: out0 = H @ W2^T (fp32 out), 128x64 tile ---------------
__launch_bounds__(256)
__global__ void gemm2_k(const ushort* __restrict__ H, const float* __restrict__ W2,
                        float* __restrict__ out) {
    __shared__ ushort sA[128 * 64];
    __shared__ ushort sB[64 * 64];
    const int m0 = blockIdx.x * 128;
    const int t = threadIdx.x;
    const int wid = t >> 6, lane = t & 63;
    const int lo = lane & 15, hi = lane >> 4;

    f32x4 acc[2][4] = {};

    for (int kt = 0; kt < N_HID; kt += 64) {
        // stage A: H tile 128x64 bf16, direct 16B copies
        #pragma unroll
        for (int p = 0; p < 4; ++p) {
            int idx = p * 256 + t;
            int row = idx >> 3, g = idx & 7;
            int grow = m0 + row; if (grow > N_NODES - 1) grow = N_NODES - 1;
            uint4 v = *reinterpret_cast<const uint4*>(H + (size_t)grow * N_HID + kt + g * 8);
            *reinterpret_cast<uint4*>(&sA[row * 64 + ((g ^ (row & 7)) << 3)]) = v;
        }
        // stage B: W2 64 rows x 64 k (fp32 -> bf16)
        #pragma unroll
        for (int p = 0; p < 4; ++p) {
            int idx = p * 256 + t;
            int row = idx >> 4, f4 = idx & 15;
            const float4 v = *reinterpret_cast<const float4*>(W2 + (size_t)row * N_HID + kt + f4 * 4);
            ushort4 h; h.x = f2bf(v.x); h.y = f2bf(v.y); h.z = f2bf(v.z); h.w = f2bf(v.w);
            int g = f4 >> 1;
            int off = row * 64 + ((g ^ (row & 7)) << 3) + ((f4 & 1) << 2);
            *reinterpret_cast<ushort4*>(&sB[off]) = h;
        }
        __syncthreads();
        #pragma unroll
        for (int kk = 0; kk < 2; ++kk) {
            const int g = kk * 4 + hi;
            s16x8 a[2], b[4];
            #pragma unroll
            for (int i = 0; i < 2; ++i) {
                int row = wid * 32 + i * 16 + lo;
                a[i] = *reinterpret_cast<const s16x8*>(&sA[row * 64 + ((g ^ (row & 7)) << 3)]);
            }
            #pragma unroll
            for (int j = 0; j < 4; ++j) {
                int row = j * 16 + lo;
                b[j] = *reinterpret_cast<const s16x8*>(&sB[row * 64 + ((g ^ (row & 7)) << 3)]);
            }
            #pragma unroll
            for (int i = 0; i < 2; ++i)
                #pragma unroll
                for (int j = 0; j < 4; ++j)
                    acc[i][j] = __builtin_amdgcn_mfma_f32_16x16x32_bf16(a[i], b[j], acc[i][j], 0, 0, 0);
        }
        __syncthreads();
    }
    #pragma unroll
    for (int i = 0; i < 2; ++i) {
        int rbase = m0 + wid * 32 + i * 16 + hi * 4;
        #pragma unroll
        for (int j = 0; j < 4; ++j) {
            int col = j * 16 + lo;
            #pragma unroll
            for (int r = 0; r < 4; ++r) {
                int row = rbase + r;
                if (row < N_NODES) out[(size_t)row * N_CLS + col] = acc[i][j][r];
            }
        }
    }
}

// ---------------- degree / dinv ------------------------------------------------
__global__ void deg_k(const int* __restrict__ dst, int* __restrict__ deg) {
    int e = blockIdx.x * 256 + threadIdx.x;
    if (e < N_EDGES) atomicAdd(&deg[dst[e]], 1);
}

__global__ void dinv_k(const int* __restrict__ deg, float* __restrict__ dinv) {
    int n = blockIdx.x * 256 + threadIdx.x;
    if (n < N_NODES) dinv[n] = rsqrtf((float)deg[n] + 1.0f);  // +1 self loop
}

// ---------------- CSR build: scan + scatter ------------------------------------
__device__ __forceinline__ int wave_incl_scan(int v, int lane) {
    #pragma unroll
    for (int d = 1; d < 64; d <<= 1) {
        int u = __shfl_up(v, d, 64);
        if (lane >= d) v += u;
    }
    return v;
}

__global__ void scan_p1(const int* __restrict__ cnt, int* __restrict__ partial) {
    int i = blockIdx.x * 256 + threadIdx.x;
    int v = (i < N_NODES) ? cnt[i] : 0;
    #pragma unroll
    for (int d = 32; d; d >>= 1) v += __shfl_xor(v, d, 64);
    __shared__ int wt[4];
    int wid = threadIdx.x >> 6, lane = threadIdx.x & 63;
    if (lane == 0) wt[wid] = v;
    __syncthreads();
    if (threadIdx.x == 0) partial[blockIdx.x] = wt[0] + wt[1] + wt[2] + wt[3];
}

__global__ void scan_p2(const int* __restrict__ partial, int* __restrict__ chunkoff,
                        int* __restrict__ row_ptr) {
    int t = threadIdx.x;
    int v = (t < 196) ? partial[t] : 0;
    int lane = t & 63, wid = t >> 6;
    int incl = wave_incl_scan(v, lane);
    __shared__ int wt[4];
    if (lane == 63) wt[wid] = incl;
    __syncthreads();
    int woff = 0;
    for (int w = 0; w < wid; ++w) woff += wt[w];
    int excl = incl - v + woff;
    if (t < 196) chunkoff[t] = excl;
    if (t == 0) row_ptr[N_NODES] = N_EDGES;
}

__global__ void scan_p3(const int* __restrict__ cnt, const int* __restrict__ chunkoff,
                        int* __restrict__ row_ptr) {
    int i = blockIdx.x * 256 + threadIdx.x;
    int v = (i < N_NODES) ? cnt[i] : 0;
    int lane = threadIdx.x & 63, wid = threadIdx.x >> 6;
    int incl = wave_incl_scan(v, lane);
    __shared__ int wt[4];
    if (lane == 63) wt[wid] = incl;
    __syncthreads();
    int woff = 0;
    for (int w = 0; w < wid; ++w) woff += wt[w];
    int excl = incl - v + woff;
    if (i < N_NODES) row_ptr[i] = chunkoff[blockIdx.x] + excl;
}

__global__ void scatter_k(const int* __restrict__ src, const int* __restrict__ dst,
                          const float* __restrict__ dinv, const int* __restrict__ row_ptr,
                          int* __restrict__ cursor, int2* __restrict__ csr) {
    int e = blockIdx.x * 256 + threadIdx.x;
    if (e >= N_EDGES) return;
    int s = src[e], d = dst[e];
    int pos = atomicAdd(&cursor[d], 1);
    csr[row_ptr[d] + pos] = make_int2(s, __float_as_int(dinv[s] * dinv[d]));
}

// ---------------- one APPNP hop ------------------------------------------------
// Wave per dst node; 64 lanes = 4 edge-slots x 16 lanes. Each lane gathers a
// float4 (16 lanes x 16B = one full 256B class-row per slot), 4 slots x unroll 4
// = 16 edges in flight per iteration. Tail edges predicated via clamped index +
// zeroed weight (no divergence). 2-step shfl_xor folds the 4 slots; lanes 0-15
// apply self-loop + teleport blend and store coalesced float4.
__launch_bounds__(256)
__global__ void hop_k(const float* __restrict__ prev, const float* __restrict__ h0,
                      float* __restrict__ next, const int2* __restrict__ csr,
                      const int* __restrict__ row_ptr, const float* __restrict__ dinv) {
    const int node = (blockIdx.x * 256 + threadIdx.x) >> 6;
    const int lane = threadIdx.x & 63;
    if (node >= N_NODES) return;
    const int beg = row_ptr[node], end = row_ptr[node + 1];
    const int eg = lane >> 4;           // edge slot 0..3
    const int cq = (lane & 15) << 2;    // class offset 0,4,...,60

    f32x4 acc = {0.f, 0.f, 0.f, 0.f};

    for (int ib = beg; ib < end; ib += 16) {
        const int i0 = ib + eg, i1 = i0 + 4, i2 = i0 + 8, i3 = i0 + 12;
        // clamp OOB slots to a valid (hot) index; zero their weight
        const int2 e0 = csr[i0 < end ? i0 : beg];
        const int2 e1 = csr[i1 < end ? i1 : beg];
        const int2 e2 = csr[i2 < end ? i2 : beg];
        const int2 e3 = csr[i3 < end ? i3 : beg];
        const float w0 = (i0 < end) ? __int_as_float(e0.y) : 0.0f;
        const float w1 = (i1 < end) ? __int_as_float(e1.y) : 0.0f;
        const float w2 = (i2 < end) ? __int_as_float(e2.y) : 0.0f;
        const float w3 = (i3 < end) ? __int_as_float(e3.y) : 0.0f;
        const f32x4 p0 = *reinterpret_cast<const f32x4*>(prev + (size_t)e0.x * N_CLS + cq);
        const f32x4 p1 = *reinterpret_cast<const f32x4*>(prev + (size_t)e1.x * N_CLS + cq);
        const f32x4 p2 = *reinterpret_cast<const f32x4*>(prev + (size_t)e2.x * N_CLS + cq);
        const f32x4 p3 = *reinterpret_cast<const f32x4*>(prev + (size_t)e3.x * N_CLS + cq);
        #pragma unroll
        for (int c = 0; c < 4; ++c) {
            acc[c] = fmaf(w0, p0[c], acc[c]);
            acc[c] = fmaf(w1, p1[c], acc[c]);
            acc[c] = fmaf(w2, p2[c], acc[c]);
            acc[c] = fmaf(w3, p3[c], acc[c]);
        }
    }

    // fold the 4 edge slots (lane bits 4 and 5)
    #pragma unroll
    for (int c = 0; c < 4; ++c) {
        acc[c] += __shfl_xor(acc[c], 16, 64);
        acc[c] += __shfl_xor(acc[c], 32, 64);
    }

    if (eg == 0) {
        const float di = dinv[node];
        const float wself = di * di;
        const size_t off = (size_t)node * N_CLS + cq;
        const f32x4 pv = *reinterpret_cast<const f32x4*>(prev + off);
        const f32x4 hh = *reinterpret_cast<const f32x4*>(h0 + off);
        f32x4 r;
        #pragma unroll
        for (int c = 0; c < 4; ++c)
            r[c] = 0.9f * fmaf(wself, pv[c], acc[c]) + 0.1f * hh[c];
        *reinterpret_cast<f32x4*>(next + off) = r;
    }
}

// ---------------- log_softmax over 64 classes, wave per row --------------------
__launch_bounds__(256)
__global__ void logsm_k(const float* __restrict__ in, float* __restrict__ out) {
    int r = (blockIdx.x * 256 + threadIdx.x) >> 6;
    int lane = threadIdx.x & 63;
    if (r >= N_NODES) return;
    float v = in[(size_t)r * N_CLS + lane];
    float m = v;
    #pragma unroll
    for (int d = 32; d; d >>= 1) m = fmaxf(m, __shfl_xor(m, d, 64));
    float e = __expf(v - m);
    float s = e;
    #pragma unroll
    for (int d = 32; d; d >>= 1) s += __shfl_xor(s, d, 64);
    out[(size_t)r * N_CLS + lane] = (v - m) - __logf(s);
}

extern "C" void kernel_launch(void* const* d_in, const int* in_sizes, int n_in,
                              void* d_out, int out_size, void* d_ws, size_t ws_size,
                              hipStream_t stream) {
    const float* X  = (const float*)d_in[0];
    const int*   EI = (const int*)d_in[1];
    const float* W1 = (const float*)d_in[2];
    const float* W2 = (const float*)d_in[3];
    const int* src = EI;
    const int* dst = EI + N_EDGES;

    char* ws = (char*)d_ws;
    ushort* H      = (ushort*)(ws + 0);            // 25,600,000 B
    float*  h0     = (float*)(ws + 25600000);      // 12,800,000 B
    float*  pp0    = (float*)(ws + 38400000);      // 12,800,000 B
    float*  pp1    = (float*)(ws + 51200000);      // 12,800,000 B
    int2*   csr    = (int2*)(ws + 64000000);       // 12,800,000 B
    int*    deg    = (int*)(ws + 76800000);        // 200,704 B
    float*  dinv   = (float*)(ws + 77000704);      // 200,704 B
    int*    rptr   = (int*)(ws + 77201408);        // 200,704 B
    int*    cursor = (int*)(ws + 77402112);        // 200,704 B
    int*    part   = (int*)(ws + 77602816);        // 1,024 B
    int*    coff   = (int*)(ws + 77603840);        // 1,024 B

    hipMemsetAsync(deg, 0, N_NODES * sizeof(int), stream);
    hipMemsetAsync(cursor, 0, N_NODES * sizeof(int), stream);

    gemm1_k<<<dim3(391, 2), 256, 0, stream>>>(X, W1, H);
    gemm2_k<<<391, 256, 0, stream>>>(H, W2, h0);

    deg_k<<<6250, 256, 0, stream>>>(dst, deg);
    dinv_k<<<196, 256, 0, stream>>>(deg, dinv);
    scan_p1<<<196, 256, 0, stream>>>(deg, part);
    scan_p2<<<1, 256, 0, stream>>>(part, coff, rptr);
    scan_p3<<<196, 256, 0, stream>>>(deg, coff, rptr);
    scatter_k<<<6250, 256, 0, stream>>>(src, dst, dinv, rptr, cursor, csr);

    const float* p = h0;
    float* bufs[2] = {pp0, pp1};
    for (int k = 0; k < K_HOPS; ++k) {
        float* nx = bufs[k & 1];
        hop_k<<<12500, 256, 0, stream>>>(p, h0, nx, csr, rptr, dinv);
        p = nx;
    }
    logsm_k<<<12500, 256, 0, stream>>>(p, (float*)d_out);
}